// Round 6
// baseline (1911.641 us; speedup 1.0000x reference)
//
#include <hip/hip_runtime.h>
#include <hip/hip_bf16.h>
#include <stdint.h>

// Problem constants (SNNExoplanetDetector): B=256 batch, T=1000 steps,
// F=128 input feats, H=256 hidden, O=2 outputs.
constexpr int B = 256, T = 1000, F = 128, H = 256, O = 2;
constexpr float DT_TAU_MEM = 0.1f;   // DT * TAU_MEM_INV
constexpr float SYN_DECAY  = 0.8f;   // 1 - DT * TAU_SYN_INV
constexpr float V_THRESH   = 1.0f;

// wT workspace layout: 4 stream regions of (1 zero row + 64 rows) x 256 floats.
// Stream s covers w_rec columns s*64 .. s*64+63 (as rows of the transpose).
constexpr int NRB = 65;                    // rows per stream region (1 zero + 64)
constexpr int WREGION_FLOATS = 4 * NRB * H;  // 66560 floats = 266240 bytes

// ---------------------------------------------------------------------------
// Storage-type adapters for xw (fp32 if workspace fits it, else bf16).
// ---------------------------------------------------------------------------
__device__ inline unsigned short f2bf_raw(float f) {
  __hip_bfloat16 b = __float2bfloat16(f);
  return *reinterpret_cast<unsigned short*>(&b);
}

template <typename XT> struct XConv;
template <> struct XConv<float> {
  static __device__ inline float load1(const float* p) { return *p; }
  static __device__ inline void store4(float* p, float a, float b, float c, float d) {
    *reinterpret_cast<float4*>(p) = make_float4(a, b, c, d);
  }
};
template <> struct XConv<__hip_bfloat16> {
  static __device__ inline float load1(const __hip_bfloat16* p) {
    unsigned u = *reinterpret_cast<const unsigned short*>(p);
    return __uint_as_float(u << 16);
  }
  static __device__ inline void store4(__hip_bfloat16* p, float a, float b, float c, float d) {
    ushort4 u = make_ushort4(f2bf_raw(a), f2bf_raw(b), f2bf_raw(c), f2bf_raw(d));
    *reinterpret_cast<ushort4*>(p) = u;
  }
};

// ---------------------------------------------------------------------------
// Transpose w_rec [h][k] -> stream regions with leading zero rows.
// grid = 4*NRB blocks; block j: stream s=j/NRB, u=j%NRB. u==0 -> zero row,
// else row k = s*64 + (u-1):  wz[j*256 + h] = w[h*256 + k].
// ---------------------------------------------------------------------------
__global__ void transpose_wrec(const float* __restrict__ w, float* __restrict__ wz) {
  int j = blockIdx.x;
  int h = threadIdx.x;
  int s = j / NRB, u = j % NRB;
  float val = 0.f;
  if (u != 0) {
    int k = s * 64 + (u - 1);
    val = w[h * H + k];
  }
  wz[(size_t)j * H + h] = val;
}

// ---------------------------------------------------------------------------
// GEMM: xw[m][n] = sum_k x[m][k] * w_in[n][k];  M = B*T = 256000, K=128, N=256
// (unchanged)
// ---------------------------------------------------------------------------
template <typename XT>
__global__ __launch_bounds__(256) void gemm_xw(const float* __restrict__ x,
                                               const float* __restrict__ w_in,
                                               XT* __restrict__ xw) {
  constexpr int K = 128;
  constexpr int SA = 68;
  __shared__ float As[K][SA];
  __shared__ float Bs[K][SA];

  const int m0 = blockIdx.x * 64;
  const int n0 = blockIdx.y * 64;
  const int tid = threadIdx.x;

  {
    const int r  = tid >> 2;
    const int cq = tid & 3;
    const float* xa = x    + (size_t)(m0 + r) * K;
    const float* xb = w_in + (size_t)(n0 + r) * K;
#pragma unroll
    for (int j = 0; j < 8; ++j) {
      const int c = (cq + (j << 2)) << 2;
      float4 av = *reinterpret_cast<const float4*>(xa + c);
      float4 bv = *reinterpret_cast<const float4*>(xb + c);
      As[c + 0][r] = av.x; As[c + 1][r] = av.y; As[c + 2][r] = av.z; As[c + 3][r] = av.w;
      Bs[c + 0][r] = bv.x; Bs[c + 1][r] = bv.y; Bs[c + 2][r] = bv.z; Bs[c + 3][r] = bv.w;
    }
  }
  __syncthreads();

  const int tn = (tid & 15) << 2;
  const int tm = (tid >> 4) << 2;
  float acc[4][4] = {};

#pragma unroll 16
  for (int k = 0; k < K; ++k) {
    float4 a = *reinterpret_cast<const float4*>(&As[k][tm]);
    float4 b = *reinterpret_cast<const float4*>(&Bs[k][tn]);
    acc[0][0] += a.x * b.x; acc[0][1] += a.x * b.y; acc[0][2] += a.x * b.z; acc[0][3] += a.x * b.w;
    acc[1][0] += a.y * b.x; acc[1][1] += a.y * b.y; acc[1][2] += a.y * b.z; acc[1][3] += a.y * b.w;
    acc[2][0] += a.z * b.x; acc[2][1] += a.z * b.y; acc[2][2] += a.z * b.z; acc[2][3] += a.z * b.w;
    acc[3][0] += a.w * b.x; acc[3][1] += a.w * b.y; acc[3][2] += a.w * b.z; acc[3][3] += a.w * b.w;
  }

#pragma unroll
  for (int im = 0; im < 4; ++im) {
    XT* p = xw + (size_t)(m0 + tm + im) * H + (n0 + tn);
    XConv<XT>::store4(p, acc[im][0], acc[im][1], acc[im][2], acc[im][3]);
  }
}

// ---------------------------------------------------------------------------
// LIF scan v4: 4-wave column-split + CROSS-STEP gather pipeline.
//   Recurrence slack: i_s = 0.8 i_{s-1} + xw_s + W z_{s-1} is first consumed
//   by v_dec at step s+1. So: issue the W-row loads for z_{s-1} at step s,
//   consume them at step s+1 -> a full step (~600cy) of latency cover.
//   Per step: [ISSUE 4x16 static slots from masks][ACC prev buffer]
//   [finalize i][LIF/ballot][1 barrier + mask exchange].
//   Static branch-free issue via zero-row padding (empty mask decodes to a
//   dedicated zero row) -> compiler emits COUNTED waitcnts, no drains.
//   Overflow (>16 spikes per 64-neuron group) -> rare uniform-branch slow
//   path that self-drains so it can't poison fast-path wait counts.
// ---------------------------------------------------------------------------

__device__ __forceinline__ uint64_t rl64(uint64_t v) {
  unsigned lo = __builtin_amdgcn_readfirstlane((unsigned)(v & 0xffffffffull));
  unsigned hi = __builtin_amdgcn_readfirstlane((unsigned)(v >> 32));
  return ((uint64_t)hi << 32) | lo;
}

// Issue 16 slots from mask M via per-lane byte pointer PTR.
// Decode: bit p -> byte offset (p+1)*1024; empty mask -> offset 0 (zero row).
#define ISSUE16(M, PTR, BUF, OFS) do {                                  \
    _Pragma("unroll")                                                   \
    for (int _i = 0; _i < 16; ++_i) {                                   \
      int p_ = (M) ? (int)__builtin_ctzll(M) : -1;                      \
      unsigned u_ = (((unsigned)p_) << 10) + 1024u;                     \
      (BUF)[(OFS) + _i] = *(const float*)((const char*)(PTR) + u_);     \
      (M) &= (M) - 1ull;                                                \
    }                                                                   \
  } while (0)

#define ACC16(BUF, OFS) do {                                            \
    _Pragma("unroll")                                                   \
    for (int _i = 0; _i < 16; ++_i) racc[_i & 3] += (BUF)[(OFS) + _i];  \
  } while (0)

#define SLOWADD(M, PTR) while (M) {                                     \
    int p_ = (int)__builtin_ctzll(M);                                   \
    unsigned u_ = (((unsigned)p_) << 10) + 1024u;                       \
    racc[0] += *(const float*)((const char*)(PTR) + u_);                \
    (M) &= (M) - 1ull;                                                  \
  }

// One pipelined LIF step.
//   IB: issue buffer (loads for G(z_{s-1}));  CB: consume buffer (G(z_{s-2}))
//   RI*: leftover masks saved for next step;  RC*: leftovers consumed now
//   PAR: mask LDS buffer parity;  XWV: xw_{s-1}
#define STEP(IB, CB, RI0, RI1, RI2, RI3, RC0, RC1, RC2, RC3, PAR, XWV) do { \
    /* phase 1: issue gather for z_{s-1} (masks from prev exchange) */      \
    uint64_t _m0 = M0, _m1 = M1, _m2 = M2, _m3 = M3;                        \
    ISSUE16(_m0, lptr0, IB, 0);                                             \
    ISSUE16(_m1, lptr1, IB, 16);                                            \
    ISSUE16(_m2, gptr2, IB, 32);                                            \
    ISSUE16(_m3, gptr3, IB, 48);                                            \
    RI0 = _m0; RI1 = _m1; RI2 = _m2; RI3 = _m3;                             \
    /* phase 2: consume prev step's buffer (global first: exact vmcnt) */   \
    float racc[4] = {0.f, 0.f, 0.f, 0.f};                                   \
    ACC16(CB, 32); ACC16(CB, 48);                                           \
    ACC16(CB, 0);  ACC16(CB, 16);                                           \
    if (__builtin_expect((RC0 | RC1 | RC2 | RC3) != 0ull, 0)) {             \
      SLOWADD(RC0, lptr0); SLOWADD(RC1, lptr1);                             \
      SLOWADD(RC2, gptr2); SLOWADD(RC3, gptr3);                             \
      __builtin_amdgcn_s_waitcnt(0); /* taken-path exits drained */         \
    }                                                                       \
    const float rec = (racc[0] + racc[1]) + (racc[2] + racc[3]);            \
    /* phase 3: finalize i_{s-1} */                                         \
    cur = cur * SYN_DECAY + (XWV) + rec;                                    \
    /* phase 4: LIF threshold for z_s */                                    \
    const float vd = v + DT_TAU_MEM * (cur - v);                            \
    const int z = vd > V_THRESH;                                            \
    v = z ? 0.f : vd;                                                       \
    ncnt += z;                                                              \
    /* phase 5: exchange masks (one barrier) */                             \
    unsigned long long bz = __ballot(z);                                    \
    if (ln == 0) mskbuf[PAR][w] = bz;                                       \
    __syncthreads();                                                        \
    M0 = rl64(mskbuf[PAR][0]); M1 = rl64(mskbuf[PAR][1]);                   \
    M2 = rl64(mskbuf[PAR][2]); M3 = rl64(mskbuf[PAR][3]);                   \
  } while (0)

template <typename XT>
__global__ __launch_bounds__(256, 1) void scan_lif(const XT* __restrict__ xw,
                                                   const float* __restrict__ wz,
                                                   const float* __restrict__ fc_w,
                                                   const float* __restrict__ fc_b,
                                                   float* __restrict__ out) {
  const int b   = blockIdx.x;
  const int tid = threadIdx.x;  // owns neuron h = tid
  const int w   = tid >> 6;     // wave 0..3
  const int ln  = tid & 63;

  // Streams 0,1 (rows 0..127 incl. their zero rows) staged in LDS: 130 rows.
  __shared__ float wlds[2 * NRB][H];         // 133120 B
  __shared__ unsigned long long mskbuf[2][4];
  __shared__ float red[8];

  {
    const float4* s4 = reinterpret_cast<const float4*>(wz);
    float4* d4 = reinterpret_cast<float4*>(&wlds[0][0]);
    for (int i = tid; i < 2 * NRB * H / 4; i += 256) d4[i] = s4[i];
  }

  // Per-lane byte pointers; decode offset 0 lands on each stream's zero row.
  const char* lptr0 = (const char*)&wlds[0][0]        + tid * 4;
  const char* lptr1 = (const char*)&wlds[NRB][0]      + tid * 4;
  const char* gptr2 = (const char*)(wz + 2 * NRB * H) + tid * 4;
  const char* gptr3 = (const char*)(wz + 3 * NRB * H) + tid * 4;

  float v = 0.f, cur = 0.f;
  int ncnt = 0;
  uint64_t M0 = 0, M1 = 0, M2 = 0, M3 = 0;
  uint64_t RA0 = 0, RA1 = 0, RA2 = 0, RA3 = 0;
  uint64_t RB0 = 0, RB1 = 0, RB2 = 0, RB3 = 0;

  float bufA[64], bufB[64];
#pragma unroll
  for (int i = 0; i < 64; ++i) { bufA[i] = 0.f; bufB[i] = 0.f; }

  const XT* xrow = xw + (size_t)b * T * H + tid;
  float xprev = 0.f;  // xw_{s-1} for the first step of each block
  float xc[8];

  __syncthreads();  // wlds visible

  for (int blk = 0; blk < 125; ++blk) {
    const XT* nx = xrow + (size_t)blk * 8 * H;
#pragma unroll
    for (int j = 0; j < 8; ++j) xc[j] = XConv<XT>::load1(nx + j * H);

    STEP(bufA, bufB, RA0, RA1, RA2, RA3, RB0, RB1, RB2, RB3, 0, xprev);
    STEP(bufB, bufA, RB0, RB1, RB2, RB3, RA0, RA1, RA2, RA3, 1, xc[0]);
    STEP(bufA, bufB, RA0, RA1, RA2, RA3, RB0, RB1, RB2, RB3, 0, xc[1]);
    STEP(bufB, bufA, RB0, RB1, RB2, RB3, RA0, RA1, RA2, RA3, 1, xc[2]);
    STEP(bufA, bufB, RA0, RA1, RA2, RA3, RB0, RB1, RB2, RB3, 0, xc[3]);
    STEP(bufB, bufA, RB0, RB1, RB2, RB3, RA0, RA1, RA2, RA3, 1, xc[4]);
    STEP(bufA, bufB, RA0, RA1, RA2, RA3, RB0, RB1, RB2, RB3, 0, xc[5]);
    STEP(bufB, bufA, RB0, RB1, RB2, RB3, RA0, RA1, RA2, RA3, 1, xc[6]);
    xprev = xc[7];
  }

  // ---- Readout: out[b][o] = sum_h count[h] * fc_w[o][h] + fc_b[o] ----
  const float cf = (float)ncnt;
#pragma unroll
  for (int o = 0; o < O; ++o) {
    float p = cf * fc_w[o * H + tid];
#pragma unroll
    for (int off = 32; off > 0; off >>= 1) p += __shfl_down(p, off, 64);
    if (ln == 0) red[o * 4 + w] = p;
    __syncthreads();
  }
  if (tid < O) {
    out[b * O + tid] =
        (red[tid * 4 + 0] + red[tid * 4 + 1] + red[tid * 4 + 2] + red[tid * 4 + 3]) + fc_b[tid];
  }
}

// ---------------------------------------------------------------------------
extern "C" void kernel_launch(void* const* d_in, const int* in_sizes, int n_in,
                              void* d_out, int out_size, void* d_ws, size_t ws_size,
                              hipStream_t stream) {
  const float* x     = (const float*)d_in[0];
  const float* w_in  = (const float*)d_in[1];
  const float* w_rec = (const float*)d_in[2];
  const float* fc_w  = (const float*)d_in[3];
  const float* fc_b  = (const float*)d_in[4];
  float* out = (float*)d_out;

  // workspace layout: [wz regions 260x256 f32][xw (fp32 if it fits, else bf16)]
  float* wz = (float*)d_ws;
  const size_t wz_bytes = (size_t)WREGION_FLOATS * sizeof(float);
  char* xw_base = (char*)d_ws + wz_bytes;
  const size_t xw_elems = (size_t)B * T * H;
  const bool use_f32 = ws_size >= wz_bytes + xw_elems * sizeof(float);

  transpose_wrec<<<4 * NRB, H, 0, stream>>>(w_rec, wz);

  if (use_f32) {
    float* xw = (float*)xw_base;
    gemm_xw<float><<<dim3(B * T / 64, H / 64), 256, 0, stream>>>(x, w_in, xw);
    scan_lif<float><<<B, 256, 0, stream>>>(xw, wz, fc_w, fc_b, out);
  } else {
    __hip_bfloat16* xw = (__hip_bfloat16*)xw_base;
    gemm_xw<__hip_bfloat16><<<dim3(B * T / 64, H / 64), 256, 0, stream>>>(x, w_in, xw);
    scan_lif<__hip_bfloat16><<<B, 256, 0, stream>>>(xw, wz, fc_w, fc_b, out);
  }
}

// Round 8
// 1598.019 us; speedup vs baseline: 1.1963x; 1.1963x over previous
//
#include <hip/hip_runtime.h>
#include <hip/hip_bf16.h>
#include <stdint.h>

// Problem constants (SNNExoplanetDetector): B=256 batch, T=1000 steps,
// F=128 input feats, H=256 hidden, O=2 outputs.
constexpr int B = 256, T = 1000, F = 128, H = 256, O = 2;
constexpr float DT_TAU_MEM = 0.1f;   // DT * TAU_MEM_INV
constexpr float SYN_DECAY  = 0.8f;   // 1 - DT * TAU_SYN_INV
constexpr float V_THRESH   = 1.0f;

typedef __attribute__((ext_vector_type(8))) _Float16 half8v;  // 8 f16 = 4 VGPR
typedef __attribute__((ext_vector_type(4))) float f32x4;      // MFMA C/D frag

// ---------------------------------------------------------------------------
// Storage-type adapters for xw (fp32 if workspace fits it, else bf16).
// ---------------------------------------------------------------------------
__device__ inline unsigned short f2bf_raw(float f) {
  __hip_bfloat16 b = __float2bfloat16(f);
  return *reinterpret_cast<unsigned short*>(&b);
}

template <typename XT> struct XConv;
template <> struct XConv<float> {
  typedef float4 Raw;
  static __device__ inline Raw loadraw(const float* p) {
    return *reinterpret_cast<const float4*>(p);
  }
  static __device__ inline float extract(const Raw& r, int i) {
    return reinterpret_cast<const float*>(&r)[i];
  }
  static __device__ inline void store4(float* p, float a, float b, float c, float d) {
    *reinterpret_cast<float4*>(p) = make_float4(a, b, c, d);
  }
};
template <> struct XConv<__hip_bfloat16> {
  typedef ushort4 Raw;
  static __device__ inline Raw loadraw(const __hip_bfloat16* p) {
    return *reinterpret_cast<const ushort4*>(p);
  }
  static __device__ inline float extract(const Raw& r, int i) {
    unsigned u = reinterpret_cast<const unsigned short*>(&r)[i];
    return __uint_as_float(u << 16);
  }
  static __device__ inline void store4(__hip_bfloat16* p, float a, float b, float c, float d) {
    ushort4 u = make_ushort4(f2bf_raw(a), f2bf_raw(b), f2bf_raw(c), f2bf_raw(d));
    *reinterpret_cast<ushort4*>(p) = u;
  }
};

// ---------------------------------------------------------------------------
// GEMM: xw[m][n] = sum_k x[m][k] * w_in[n][k];  M = B*T = 256000, K=128, N=256
// (unchanged -- keeps xw bit-identical to the passing rounds)
// ---------------------------------------------------------------------------
template <typename XT>
__global__ __launch_bounds__(256) void gemm_xw(const float* __restrict__ x,
                                               const float* __restrict__ w_in,
                                               XT* __restrict__ xw) {
  constexpr int K = 128;
  constexpr int SA = 68;
  __shared__ float As[K][SA];
  __shared__ float Bs[K][SA];

  const int m0 = blockIdx.x * 64;
  const int n0 = blockIdx.y * 64;
  const int tid = threadIdx.x;

  {
    const int r  = tid >> 2;
    const int cq = tid & 3;
    const float* xa = x    + (size_t)(m0 + r) * K;
    const float* xb = w_in + (size_t)(n0 + r) * K;
#pragma unroll
    for (int j = 0; j < 8; ++j) {
      const int c = (cq + (j << 2)) << 2;
      float4 av = *reinterpret_cast<const float4*>(xa + c);
      float4 bv = *reinterpret_cast<const float4*>(xb + c);
      As[c + 0][r] = av.x; As[c + 1][r] = av.y; As[c + 2][r] = av.z; As[c + 3][r] = av.w;
      Bs[c + 0][r] = bv.x; Bs[c + 1][r] = bv.y; Bs[c + 2][r] = bv.z; Bs[c + 3][r] = bv.w;
    }
  }
  __syncthreads();

  const int tn = (tid & 15) << 2;
  const int tm = (tid >> 4) << 2;
  float acc[4][4] = {};

#pragma unroll 16
  for (int k = 0; k < K; ++k) {
    float4 a = *reinterpret_cast<const float4*>(&As[k][tm]);
    float4 b = *reinterpret_cast<const float4*>(&Bs[k][tn]);
    acc[0][0] += a.x * b.x; acc[0][1] += a.x * b.y; acc[0][2] += a.x * b.z; acc[0][3] += a.x * b.w;
    acc[1][0] += a.y * b.x; acc[1][1] += a.y * b.y; acc[1][2] += a.y * b.z; acc[1][3] += a.y * b.w;
    acc[2][0] += a.z * b.x; acc[2][1] += a.z * b.y; acc[2][2] += a.z * b.z; acc[2][3] += a.z * b.w;
    acc[3][0] += a.w * b.x; acc[3][1] += a.w * b.y; acc[3][2] += a.w * b.z; acc[3][3] += a.w * b.w;
  }

#pragma unroll
  for (int im = 0; im < 4; ++im) {
    XT* p = xw + (size_t)(m0 + tm + im) * H + (n0 + tn);
    XConv<XT>::store4(p, acc[im][0], acc[im][1], acc[im][2], acc[im][3]);
  }
}

// ---------------------------------------------------------------------------
// LIF scan v6: dense MFMA recurrence with EXACT-SPLIT W (2 x f16).
//   rec[256h x 16g] = w_rec . Z,  Z = spikes (f16 0/1).
//   W*2^10 = hi + 2^-12 * mid, both f16 RNE:
//     hi = f16(w*1024); r = w*1024 - hi (exact fp32); mid = f16(r*4096).
//   residual <= 2^-22 |w| -> rec error ~ fp32 ordering-noise class (the same
//   class rounds 3-6 passed with absmax 0.0). Round 7's single-bf16 W
//   (2^-8 |w|) produced a handful of spike flips -> absmax 2.375.
//   Two MFMA chains (hi, mid) share the Z fragments; 64 mfma/step/wave.
//   Layouts identical to round 7 (verified: error signature was numeric,
//   not positional).
// ---------------------------------------------------------------------------

template <typename XT>
__global__ __launch_bounds__(256, 1) void scan_lif(const XT* __restrict__ xw,
                                                   const float* __restrict__ w_rec,
                                                   const float* __restrict__ fc_w,
                                                   const float* __restrict__ fc_b,
                                                   float* __restrict__ out) {
  const int tid = threadIdx.x;
  const int w  = tid >> 6;   // wave 0..3: W rows 64w..64w+63
  const int l  = tid & 63;
  const int lg = l & 15;     // A-row-in-tile / D-col (batch) / Z row
  const int lk = l >> 4;     // k-group / D row-group
  const int g0 = blockIdx.x * 16;

  // Z[g][k] as f16, row stride 264 shorts (528B, 16B-aligned rows).
  __shared__ unsigned short Zb[2][16][264];
  __shared__ float red[16][2];

  {
    unsigned* p = reinterpret_cast<unsigned*>(&Zb[0][0][0]);
    for (int i = tid; i < (int)(sizeof(Zb) / 4); i += 256) p[i] = 0u;
  }
  if (tid < 32) (&red[0][0])[tid] = 0.f;

  // ---- Load W into split f16 A-fragments, once. ----
  half8v afr_h[4][8], afr_m[4][8];
#pragma unroll
  for (int rt = 0; rt < 4; ++rt) {
    const float* wrow = w_rec + (size_t)(64 * w + 16 * rt + lg) * H + 8 * lk;
#pragma unroll
    for (int ks = 0; ks < 8; ++ks) {
      half8v fh, fm;
#pragma unroll
      for (int e = 0; e < 8; ++e) {
        const float ws = wrow[32 * ks + e] * 1024.f;   // exact (pow2)
        const _Float16 h = (_Float16)ws;               // RNE
        const float r = ws - (float)h;                 // exact in fp32
        fh[e] = h;
        fm[e] = (_Float16)(r * 4096.f);                // RNE, scaled to normal
      }
      afr_h[rt][ks] = fh;
      afr_m[rt][ks] = fm;
    }
  }

  // ---- LIF state: lane owns (h = 64w+16rt+4lk+r, g = g0+lg), i = rt*4+r ----
  float v[16], cur[16];
  int   cnt[16];
#pragma unroll
  for (int i = 0; i < 16; ++i) { v[i] = 0.f; cur[i] = 0.f; cnt[i] = 0; }

  const XT* xb = xw + (size_t)(g0 + lg) * T * H + 64 * w + 4 * lk;

  typename XConv<XT>::Raw xr0[4], xr1[4];
#pragma unroll
  for (int rt = 0; rt < 4; ++rt) xr0[rt] = XConv<XT>::loadraw(xb + 0 * H + 16 * rt);
#pragma unroll
  for (int rt = 0; rt < 4; ++rt) xr1[rt] = XConv<XT>::loadraw(xb + 1 * H + 16 * rt);

  __syncthreads();  // Z zero + red zero visible

  // One LIF step: consume XR (= xw_t), read Z buf RD (= z_{t-1}), write z_t
  // into buf WR. Exactly one barrier.
#define LSTEP(XR, RD, WR) do {                                                 \
    f32x4 ach[4], acm[4];                                                      \
    _Pragma("unroll")                                                          \
    for (int rt = 0; rt < 4; ++rt) {                                           \
      ach[rt] = (f32x4){0.f, 0.f, 0.f, 0.f};                                   \
      acm[rt] = (f32x4){0.f, 0.f, 0.f, 0.f};                                   \
    }                                                                          \
    _Pragma("unroll")                                                          \
    for (int ksg = 0; ksg < 2; ++ksg) {                                        \
      half8v bf[4];                                                            \
      _Pragma("unroll")                                                        \
      for (int k2 = 0; k2 < 4; ++k2)                                           \
        bf[k2] = *reinterpret_cast<const half8v*>(                             \
            &Zb[RD][lg][32 * (4 * ksg + k2) + 8 * lk]);                        \
      _Pragma("unroll")                                                        \
      for (int k2 = 0; k2 < 4; ++k2) {                                         \
        const int ks = 4 * ksg + k2;                                           \
        _Pragma("unroll")                                                      \
        for (int rt = 0; rt < 4; ++rt) {                                       \
          ach[rt] = __builtin_amdgcn_mfma_f32_16x16x32_f16(afr_h[rt][ks],      \
                        bf[k2], ach[rt], 0, 0, 0);                             \
          acm[rt] = __builtin_amdgcn_mfma_f32_16x16x32_f16(afr_m[rt][ks],      \
                        bf[k2], acm[rt], 0, 0, 0);                             \
        }                                                                      \
      }                                                                        \
    }                                                                          \
    _Pragma("unroll")                                                          \
    for (int rt = 0; rt < 4; ++rt) {                                           \
      ushort4 zw;                                                              \
      _Pragma("unroll")                                                        \
      for (int r = 0; r < 4; ++r) {                                            \
        const int i = rt * 4 + r;                                              \
        const float rec = (ach[rt][r] + acm[rt][r] * (1.f / 4096.f))           \
                          * (1.f / 1024.f);                                    \
        const float xt = XConv<XT>::extract(XR[rt], r);                        \
        const float vd = v[i] + DT_TAU_MEM * (cur[i] - v[i]);                  \
        const int z = vd > V_THRESH;                                           \
        v[i] = z ? 0.f : vd;                                                   \
        cur[i] = cur[i] * SYN_DECAY + xt + rec;                                \
        cnt[i] += z;                                                           \
        reinterpret_cast<unsigned short*>(&zw)[r] = z ? 0x3C00u : 0u;          \
      }                                                                        \
      *reinterpret_cast<ushort4*>(&Zb[WR][lg][64 * w + 16 * rt + 4 * lk]) = zw; \
    }                                                                          \
    __syncthreads();                                                           \
  } while (0)

  for (int j = 0; j < 500; ++j) {
    LSTEP(xr0, 0, 1);   // step 2j: reads z from buf0, writes buf1
    {
      const size_t t2 = (2 * j + 2 < T) ? (size_t)(2 * j + 2) : (size_t)(T - 1);
#pragma unroll
      for (int rt = 0; rt < 4; ++rt) xr0[rt] = XConv<XT>::loadraw(xb + t2 * H + 16 * rt);
    }
    LSTEP(xr1, 1, 0);   // step 2j+1: reads buf1, writes buf0
    {
      const size_t t3 = (2 * j + 3 < T) ? (size_t)(2 * j + 3) : (size_t)(T - 1);
#pragma unroll
      for (int rt = 0; rt < 4; ++rt) xr1[rt] = XConv<XT>::loadraw(xb + t3 * H + 16 * rt);
    }
  }
#undef LSTEP

  // ---- Readout: out[g][o] = sum_h cnt[h,g] * fc_w[o][h] + fc_b[o] ----
  float po0 = 0.f, po1 = 0.f;
#pragma unroll
  for (int rt = 0; rt < 4; ++rt)
#pragma unroll
    for (int r = 0; r < 4; ++r) {
      const int h = 64 * w + 16 * rt + 4 * lk + r;
      const float c = (float)cnt[rt * 4 + r];
      po0 += c * fc_w[h];
      po1 += c * fc_w[H + h];
    }
  atomicAdd(&red[lg][0], po0);
  atomicAdd(&red[lg][1], po1);
  __syncthreads();
  if (tid < 32) {
    const int g = tid >> 1, o = tid & 1;
    out[(size_t)(g0 + g) * O + o] = red[g][o] + fc_b[o];
  }
}

// ---------------------------------------------------------------------------
extern "C" void kernel_launch(void* const* d_in, const int* in_sizes, int n_in,
                              void* d_out, int out_size, void* d_ws, size_t ws_size,
                              hipStream_t stream) {
  const float* x     = (const float*)d_in[0];
  const float* w_in  = (const float*)d_in[1];
  const float* w_rec = (const float*)d_in[2];
  const float* fc_w  = (const float*)d_in[3];
  const float* fc_b  = (const float*)d_in[4];
  float* out = (float*)d_out;

  // workspace: xw only (w_rec consumed in native layout by scan_lif)
  const size_t xw_elems = (size_t)B * T * H;
  const bool use_f32 = ws_size >= xw_elems * sizeof(float);

  if (use_f32) {
    float* xw = (float*)d_ws;
    gemm_xw<float><<<dim3(B * T / 64, H / 64), 256, 0, stream>>>(x, w_in, xw);
    scan_lif<float><<<B / 16, 256, 0, stream>>>(xw, w_rec, fc_w, fc_b, out);
  } else {
    __hip_bfloat16* xw = (__hip_bfloat16*)d_ws;
    gemm_xw<__hip_bfloat16><<<dim3(B * T / 64, H / 64), 256, 0, stream>>>(x, w_in, xw);
    scan_lif<__hip_bfloat16><<<B / 16, 256, 0, stream>>>(xw, w_rec, fc_w, fc_b, out);
  }
}